// Round 1
// baseline (3494.257 us; speedup 1.0000x reference)
//
#include <hip/hip_runtime.h>
#include <math.h>

// ---- static problem config (mirrors reference) ----
#define T_TOK 1024
#define HID   1024
#define NE    32
#define NGRP  4
#define NL    16
#define TOPK  6
#define MOEI  512
#define AI    256
#define SHI   512
#define RSCALE 0.2f
#define AALPHA 0.1f
#define HK 32          // H-chunk staged in LDS per iteration

__device__ __forceinline__ void atomAddF(float* p, float v) {
    unsafeAtomicAdd(p, v);   // HW global_atomic_add_f32 on gfx950
}

__global__ void zero_kernel(float* __restrict__ out, int n, int* __restrict__ c, int nc) {
    int i = blockIdx.x * blockDim.x + threadIdx.x;
    if (i < n) out[i] = 0.f;
    if (i < nc) c[i] = 0;
}

// One block (256 threads) per token: logits -> sigmoid -> group-limited top-6
// -> normalized weights; appends token to per-expert and per-anchor-group lists.
__global__ __launch_bounds__(256) void router_kernel(
    const float* __restrict__ x, const float* __restrict__ gw, const float* __restrict__ gb,
    int* __restrict__ ecnt, int* __restrict__ acnt,
    int* __restrict__ elist, float* __restrict__ ewt, int* __restrict__ alist)
{
    const int t = blockIdx.x;
    __shared__ float xs[HID];
    __shared__ float logits[NE];
    const int tid = threadIdx.x;
    ((float4*)xs)[tid] = ((const float4*)(x + (size_t)t * HID))[tid];
    __syncthreads();

    const int e = tid >> 3, sub = tid & 7;           // 8 threads per expert
    const float4* wp = (const float4*)(gw + (size_t)e * HID + sub * 128);
    const float4* xp = (const float4*)(xs + sub * 128);
    float s = 0.f;
    #pragma unroll
    for (int i = 0; i < 32; ++i) {
        float4 a = xp[i], b = wp[i];
        s = fmaf(a.x, b.x, s); s = fmaf(a.y, b.y, s);
        s = fmaf(a.z, b.z, s); s = fmaf(a.w, b.w, s);
    }
    s += __shfl_xor(s, 1); s += __shfl_xor(s, 2); s += __shfl_xor(s, 4);
    if (sub == 0) logits[e] = s;
    __syncthreads();

    if (tid == 0) {   // serial scoring: 32 elements, trivial; exact jax top_k tie semantics
        float raw[NE], sc[NE];
        #pragma unroll
        for (int i = 0; i < NE; ++i) {
            float sg = 1.f / (1.f + expf(-logits[i]));
            raw[i] = sg; sc[i] = sg + gb[i];
        }
        // per-group sum of top-2
        float gsc[NGRP];
        for (int g = 0; g < NGRP; ++g) {
            const float* p = sc + g * 8;
            float m1 = -1e30f; int i1 = 0;
            for (int i = 0; i < 8; ++i) if (p[i] > m1) { m1 = p[i]; i1 = i; }
            float m2 = -1e30f;
            for (int i = 0; i < 8; ++i) if (i != i1 && p[i] > m2) m2 = p[i];
            gsc[g] = m1 + m2;
        }
        // top-2 groups (strict >, earliest index on tie -- matches lax.top_k)
        int g1 = 0; float b1 = gsc[0];
        for (int g = 1; g < NGRP; ++g) if (gsc[g] > b1) { b1 = gsc[g]; g1 = g; }
        int g2 = 0; float b2 = -1e30f;
        for (int g = 0; g < NGRP; ++g) if (g != g1 && gsc[g] > b2) { b2 = gsc[g]; g2 = g; }
        // top-6 experts within allowed groups
        int idx[TOPK]; float tw[TOPK]; float wsum = 0.f;
        unsigned used = 0u;
        for (int k = 0; k < TOPK; ++k) {
            float best = -1e30f; int bi = 0;
            for (int i = 0; i < NE; ++i) {
                int g = i >> 3;
                if ((g == g1 || g == g2) && !((used >> i) & 1u) && sc[i] > best) { best = sc[i]; bi = i; }
            }
            used |= 1u << bi;
            idx[k] = bi; tw[k] = raw[bi]; wsum += raw[bi];
        }
        float inv = RSCALE / (wsum + 1e-20f);
        for (int k = 0; k < TOPK; ++k) {
            int ee = idx[k];
            int pos = atomicAdd(&ecnt[ee], 1);
            elist[ee * T_TOK + pos] = t;
            ewt[ee * T_TOK + pos] = tw[k] * inv;
        }
        int lg = idx[0] >> 1;                       // top-1 expert / (E/L)
        int pos = atomicAdd(&acnt[lg], 1);
        alist[lg * T_TOK + pos] = t;
    }
}

// Fused gathered SwiGLU FFN + weighted scatter-add.
// Block = (token tile tj of BTT rows) x (unit u) x (ITILE slice i0 of intermediate).
// Threads: 8 row-groups x 32 col-groups; each thread owns (BTT/8) rows x 8 cols.
template <int BTT>
__global__ __launch_bounds__(256) void ffn_kernel(
    const float* __restrict__ x,
    const float* __restrict__ wg_base, const float* __restrict__ wu_base,
    const float* __restrict__ wd_base, const int I,
    const int* __restrict__ counts, const int* __restrict__ lists,
    const float* __restrict__ wlists, const float wscale,
    float* __restrict__ out)
{
    constexpr int RPT   = BTT / 8;     // rows per thread
    constexpr int ITILE = 256;
    constexpr int NSEG  = 256 / BTT;   // threads cooperating per x row
    constexpr int FPT   = HK / NSEG;   // floats per thread in x load

    __shared__ float xs[BTT * 33];           // HK=32 cols, stride 33 (bank spread)
    __shared__ float act[BTT * ITILE];
    __shared__ int   trow_s[BTT];
    __shared__ float wt_s[BTT];

    const int u = blockIdx.y;
    const int count = counts ? counts[u] : T_TOK;
    const int tj = blockIdx.x;
    if (tj * BTT >= count) return;           // uniform early-exit
    const int i0 = blockIdx.z * ITILE;

    const float* wg = wg_base + (size_t)u * HID * I + i0;
    const float* wu = wu_base + (size_t)u * HID * I + i0;
    const float* wd = wd_base + (size_t)u * I * HID + (size_t)i0 * HID;
    const int*   lst = lists  ? lists  + (size_t)u * T_TOK : nullptr;
    const float* wl  = wlists ? wlists + (size_t)u * T_TOK : nullptr;

    const int tid = threadIdx.x;
    if (tid < BTT) {
        int idx = tj * BTT + tid;
        int trow = -1; float w = 0.f;
        if (idx < count) {
            trow = lst ? lst[idx] : idx;
            w = (wl ? wl[idx] : 1.f) * wscale;
        }
        trow_s[tid] = trow; wt_s[tid] = w;
    }
    __syncthreads();

    const int tr = tid >> 5, tc = tid & 31;
    const int lr = tid / NSEG;
    const int ls = (tid % NSEG) * FPT;
    const int ltrow = trow_s[lr];

    float accg[RPT][8], accu[RPT][8];
    #pragma unroll
    for (int rr = 0; rr < RPT; ++rr)
        #pragma unroll
        for (int cc = 0; cc < 8; ++cc) { accg[rr][cc] = 0.f; accu[rr][cc] = 0.f; }

    // ---- phase 1: gate & up GEMMs over H, X chunks staged in LDS ----
    for (int h0 = 0; h0 < HID; h0 += HK) {
        __syncthreads();
        {
            float tmp[FPT];
            if (ltrow >= 0) {
                const float* xp = x + (size_t)ltrow * HID + h0 + ls;
                #pragma unroll
                for (int j = 0; j < FPT; ++j) tmp[j] = xp[j];
            } else {
                #pragma unroll
                for (int j = 0; j < FPT; ++j) tmp[j] = 0.f;
            }
            float* xd = xs + lr * 33 + ls;
            #pragma unroll
            for (int j = 0; j < FPT; ++j) xd[j] = tmp[j];
        }
        __syncthreads();
        for (int kk = 0; kk < HK; ++kk) {
            float xv[RPT];
            #pragma unroll
            for (int rr = 0; rr < RPT; ++rr) xv[rr] = xs[(tr * RPT + rr) * 33 + kk];
            const float* wgp = wg + (size_t)(h0 + kk) * I + tc * 8;
            const float* wup = wu + (size_t)(h0 + kk) * I + tc * 8;
            float4 g0 = ((const float4*)wgp)[0], g1 = ((const float4*)wgp)[1];
            float4 u0 = ((const float4*)wup)[0], u1 = ((const float4*)wup)[1];
            float wgv[8] = {g0.x,g0.y,g0.z,g0.w,g1.x,g1.y,g1.z,g1.w};
            float wuv[8] = {u0.x,u0.y,u0.z,u0.w,u1.x,u1.y,u1.z,u1.w};
            #pragma unroll
            for (int cc = 0; cc < 8; ++cc)
                #pragma unroll
                for (int rr = 0; rr < RPT; ++rr) {
                    accg[rr][cc] = fmaf(xv[rr], wgv[cc], accg[rr][cc]);
                    accu[rr][cc] = fmaf(xv[rr], wuv[cc], accu[rr][cc]);
                }
        }
    }

    // ---- silu(gate)*up -> act (LDS) ----
    #pragma unroll
    for (int rr = 0; rr < RPT; ++rr)
        #pragma unroll
        for (int cc = 0; cc < 8; ++cc) {
            float g = accg[rr][cc];
            float sig = 1.f / (1.f + expf(-g));
            act[(tr * RPT + rr) * ITILE + tc * 8 + cc] = g * sig * accu[rr][cc];
        }
    __syncthreads();

    // ---- phase 2: down-proj, 256-col output chunks, weighted atomic scatter ----
    for (int hc = 0; hc < HID; hc += 256) {
        float acc[RPT][8];
        #pragma unroll
        for (int rr = 0; rr < RPT; ++rr)
            #pragma unroll
            for (int cc = 0; cc < 8; ++cc) acc[rr][cc] = 0.f;
        for (int kk = 0; kk < ITILE; ++kk) {
            float xv[RPT];
            #pragma unroll
            for (int rr = 0; rr < RPT; ++rr) xv[rr] = act[(tr * RPT + rr) * ITILE + kk];
            const float* wdp = wd + (size_t)kk * HID + hc + tc * 8;
            float4 w0 = ((const float4*)wdp)[0], w1 = ((const float4*)wdp)[1];
            float wv[8] = {w0.x,w0.y,w0.z,w0.w,w1.x,w1.y,w1.z,w1.w};
            #pragma unroll
            for (int cc = 0; cc < 8; ++cc)
                #pragma unroll
                for (int rr = 0; rr < RPT; ++rr)
                    acc[rr][cc] = fmaf(xv[rr], wv[cc], acc[rr][cc]);
        }
        #pragma unroll
        for (int rr = 0; rr < RPT; ++rr) {
            int trow = trow_s[tr * RPT + rr];
            if (trow >= 0) {
                float w = wt_s[tr * RPT + rr];
                float* op = out + (size_t)trow * HID + hc + tc * 8;
                #pragma unroll
                for (int cc = 0; cc < 8; ++cc) atomAddF(&op[cc], w * acc[rr][cc]);
            }
        }
    }
}

extern "C" void kernel_launch(void* const* d_in, const int* in_sizes, int n_in,
                              void* d_out, int out_size, void* d_ws, size_t ws_size,
                              hipStream_t stream) {
    const float* x   = (const float*)d_in[0];
    const float* gw  = (const float*)d_in[1];
    const float* gb  = (const float*)d_in[2];
    const float* wgt = (const float*)d_in[3];
    const float* wup = (const float*)d_in[4];
    const float* wdn = (const float*)d_in[5];
    const float* shg = (const float*)d_in[6];
    const float* shu = (const float*)d_in[7];
    const float* shd = (const float*)d_in[8];
    const float* ag  = (const float*)d_in[9];
    const float* au  = (const float*)d_in[10];
    const float* ad  = (const float*)d_in[11];
    float* out = (float*)d_out;

    // workspace layout (ints): [ecnt 32][acnt 16][pad 16][elist 32*1024][ewt 32*1024][alist 16*1024]
    int*   ecnt  = (int*)d_ws;
    int*   acnt  = ecnt + NE;
    int*   elist = ecnt + 64;
    float* ewt   = (float*)(elist + NE * T_TOK);
    int*   alist = (int*)(ewt + NE * T_TOK);

    zero_kernel<<<dim3((T_TOK * HID + 255) / 256), dim3(256), 0, stream>>>(
        out, T_TOK * HID, ecnt, NE + NL);
    router_kernel<<<dim3(T_TOK), dim3(256), 0, stream>>>(
        x, gw, gb, ecnt, acnt, elist, ewt, alist);
    // shared expert: dense over all tokens, I=512 (z=2 slices)
    ffn_kernel<16><<<dim3(T_TOK / 16, 1, 2), dim3(256), 0, stream>>>(
        x, shg, shu, shd, SHI, nullptr, nullptr, nullptr, 1.f, out);
    // routed experts: gathered lists, per-assignment weights
    ffn_kernel<32><<<dim3(T_TOK / 32, NE, 2), dim3(256), 0, stream>>>(
        x, wgt, wup, wdn, MOEI, ecnt, elist, ewt, 1.f, out);
    // anchor experts: gathered by top-1 group, weight = ANCHOR_ALPHA, I=256 (z=1)
    ffn_kernel<16><<<dim3(T_TOK / 16, NL, 1), dim3(256), 0, stream>>>(
        x, ag, au, ad, AI, acnt, alist, nullptr, AALPHA, out);
}

// Round 2
// 773.302 us; speedup vs baseline: 4.5186x; 4.5186x over previous
//
#include <hip/hip_runtime.h>
#include <math.h>

// ---- static problem config (mirrors reference) ----
#define T_TOK 1024
#define HID   1024
#define NE    32
#define NGRP  4
#define NL    16
#define TOPK  6
#define MOEI  512
#define AI    256
#define SHI   512
#define RSCALE 0.2f
#define AALPHA 0.1f
#define HK 32

typedef unsigned short u16;
typedef unsigned int   u32;
typedef __attribute__((ext_vector_type(8))) short bf16x8;
typedef __attribute__((ext_vector_type(4))) float f32x4;

__device__ __forceinline__ void atomAddF(float* p, float v) {
    unsafeAtomicAdd(p, v);   // HW global_atomic_add_f32 on gfx950
}

__device__ __forceinline__ u16 f2bf(float f) {          // fp32 -> bf16 RN-even
    u32 u = __float_as_uint(f);
    u += 0x7FFFu + ((u >> 16) & 1u);
    return (u16)(u >> 16);
}

// swizzled LDS fragment read: row-major tile, byte ^= (row&7)<<4 spreads banks
__device__ __forceinline__ bf16x8 lds_frag(const u16* buf, int row, int k, int rowBytes) {
    int byte = row * rowBytes + k * 2;
    byte ^= (row & 7) << 4;
    return *(const bf16x8*)((const char*)buf + byte);
}

// ======================= common: zero + router =======================

__global__ void zero_kernel(float* __restrict__ out, int n, int* __restrict__ c, int nc) {
    int i = blockIdx.x * blockDim.x + threadIdx.x;
    if (i < n) out[i] = 0.f;
    if (i < nc) c[i] = 0;
}

__global__ void zc_kernel(int* __restrict__ c) {
    if (threadIdx.x < 64) c[threadIdx.x] = 0;
}

__global__ __launch_bounds__(256) void router_kernel(
    const float* __restrict__ x, const float* __restrict__ gw, const float* __restrict__ gb,
    int* __restrict__ ecnt, int* __restrict__ acnt,
    int* __restrict__ elist, float* __restrict__ ewt, int* __restrict__ alist)
{
    const int t = blockIdx.x;
    __shared__ float xs[HID];
    __shared__ float logits[NE];
    const int tid = threadIdx.x;
    ((float4*)xs)[tid] = ((const float4*)(x + (size_t)t * HID))[tid];
    __syncthreads();

    const int e = tid >> 3, sub = tid & 7;
    const float4* wp = (const float4*)(gw + (size_t)e * HID + sub * 128);
    const float4* xp = (const float4*)(xs + sub * 128);
    float s = 0.f;
    #pragma unroll
    for (int i = 0; i < 32; ++i) {
        float4 a = xp[i], b = wp[i];
        s = fmaf(a.x, b.x, s); s = fmaf(a.y, b.y, s);
        s = fmaf(a.z, b.z, s); s = fmaf(a.w, b.w, s);
    }
    s += __shfl_xor(s, 1); s += __shfl_xor(s, 2); s += __shfl_xor(s, 4);
    if (sub == 0) logits[e] = s;
    __syncthreads();

    if (tid == 0) {
        float raw[NE], sc[NE];
        #pragma unroll
        for (int i = 0; i < NE; ++i) {
            float sg = 1.f / (1.f + expf(-logits[i]));
            raw[i] = sg; sc[i] = sg + gb[i];
        }
        float gsc[NGRP];
        for (int g = 0; g < NGRP; ++g) {
            const float* p = sc + g * 8;
            float m1 = -1e30f; int i1 = 0;
            for (int i = 0; i < 8; ++i) if (p[i] > m1) { m1 = p[i]; i1 = i; }
            float m2 = -1e30f;
            for (int i = 0; i < 8; ++i) if (i != i1 && p[i] > m2) m2 = p[i];
            gsc[g] = m1 + m2;
        }
        int g1 = 0; float b1 = gsc[0];
        for (int g = 1; g < NGRP; ++g) if (gsc[g] > b1) { b1 = gsc[g]; g1 = g; }
        int g2 = 0; float b2 = -1e30f;
        for (int g = 0; g < NGRP; ++g) if (g != g1 && gsc[g] > b2) { b2 = gsc[g]; g2 = g; }
        int idx[TOPK]; float tw[TOPK]; float wsum = 0.f;
        unsigned used = 0u;
        for (int k = 0; k < TOPK; ++k) {
            float best = -1e30f; int bi = 0;
            for (int i = 0; i < NE; ++i) {
                int g = i >> 3;
                if ((g == g1 || g == g2) && !((used >> i) & 1u) && sc[i] > best) { best = sc[i]; bi = i; }
            }
            used |= 1u << bi;
            idx[k] = bi; tw[k] = raw[bi]; wsum += raw[bi];
        }
        float inv = RSCALE / (wsum + 1e-20f);
        for (int k = 0; k < TOPK; ++k) {
            int ee = idx[k];
            int pos = atomicAdd(&ecnt[ee], 1);
            elist[ee * T_TOK + pos] = t;
            ewt[ee * T_TOK + pos] = tw[k] * inv;
        }
        int lg = idx[0] >> 1;
        int pos = atomicAdd(&acnt[lg], 1);
        alist[lg * T_TOK + pos] = t;
    }
}

// ======================= bf16 pre-conversion =======================

__global__ void convx_kernel(const float* __restrict__ x, u16* __restrict__ xb) {
    int i = blockIdx.x * 256 + threadIdx.x;
    float4 v = ((const float4*)x)[i];
    ushort4 o;
    o.x = f2bf(v.x); o.y = f2bf(v.y); o.z = f2bf(v.z); o.w = f2bf(v.w);
    ((ushort4*)xb)[i] = o;
}

// transpose+convert: in fp32 [nm][R][C] -> out bf16 [nm][C][R].  Tile 64(R) x 32(C).
struct TD { const float* in; u16* out; int R, C, nm, tile0; };
struct TDs { TD d[9]; };

__global__ __launch_bounds__(256) void tconv_kernel(TDs P) {
    __shared__ u16 tile[32][65];
    int t = blockIdx.x;
    int di = 0;
    #pragma unroll
    for (int i = 1; i < 9; ++i) if (t >= P.d[i].tile0) di = i;
    const float* in = P.d[di].in;
    u16* outp = P.d[di].out;
    const int R = P.d[di].R, C = P.d[di].C;
    int lt = t - P.d[di].tile0;
    int tpm = (R / 64) * (C / 32);
    int m = lt / tpm, rem = lt % tpm;
    int ct = C / 32;
    int r0 = (rem / ct) * 64, c0 = (rem % ct) * 32;
    in   += (size_t)m * R * C;
    outp += (size_t)m * R * C;
    const int tid = threadIdx.x;
    {
        int cc = tid & 31, rr0 = tid >> 5;
        #pragma unroll
        for (int j = 0; j < 8; ++j) {
            int rr = rr0 + j * 8;
            tile[cc][rr] = f2bf(in[(size_t)(r0 + rr) * C + c0 + cc]);
        }
    }
    __syncthreads();
    {
        int rr = tid & 63, cc0 = tid >> 6;
        #pragma unroll
        for (int j = 0; j < 8; ++j) {
            int c2 = cc0 + j * 4;
            outp[(size_t)(c0 + c2) * R + r0 + rr] = tile[c2][rr];
        }
    }
}

// ======================= bf16 MFMA fused FFN =======================
// Per block: 32 gathered tokens x full I.  Phase1: act = silu(X Wg) * (X Wu)
// (Wg/Wu transposed [I][H] so B-frags are row-contiguous).  Phase2:
// out += diag(w) act Wd  (Wd transposed [H][I]).  MFMA 16x16x32 bf16,
// XOR-swizzled LDS tiles, fp32 accum, bf16 act.

template<int I, bool STORE>
__global__ __launch_bounds__(256) void ffn_bf16_kernel(
    const u16* __restrict__ xb,   // [T][H] bf16
    const u16* __restrict__ wgt,  // [nm][I][H] bf16 (transposed)
    const u16* __restrict__ wut,  // [nm][I][H]
    const u16* __restrict__ wdt,  // [nm][H][I]
    const int* __restrict__ counts, const int* __restrict__ lists,
    const float* __restrict__ wlists, const float wscale,
    float* __restrict__ out)
{
    constexpr int BT = 32, NC = 128, BK = 64;
    static_assert(I % NC == 0 && I % BK == 0, "tiling");
    __shared__ __align__(16) u16 xs[BT * BK];        // 4 KB
    __shared__ __align__(16) u16 ws[2 * NC * BK];    // 32 KB (wg|wu, or wd in ph2)
    __shared__ __align__(16) u16 act[BT * I];        // 16/32 KB
    __shared__ int   trow_s[BT];
    __shared__ float wt_s[BT];

    const int u = blockIdx.y;
    const int count = counts ? counts[u] : T_TOK;
    const int tj = blockIdx.x;
    if (tj * BT >= count) return;

    const int tid = threadIdx.x;
    if (tid < BT) {
        int idx = tj * BT + tid; int trow = -1; float w = 0.f;
        if (idx < count) {
            trow = lists ? lists[u * T_TOK + idx] : idx;
            w = (wlists ? wlists[u * T_TOK + idx] : 1.f) * wscale;
        }
        trow_s[tid] = trow; wt_s[tid] = w;
    }
    __syncthreads();

    const int wid = tid >> 6, l = tid & 63, l15 = l & 15, lg = l >> 4;
    const int xr = tid >> 3, xslot = tid & 7;
    int srow = trow_s[xr]; if (srow < 0) srow = trow_s[0];   // pad rows read a valid row
    const u16* xrow_ptr = xb + (size_t)srow * HID;
    const int xdst = ((xr * BK + xslot * 8) * 2) ^ ((xr & 7) << 4);

    const size_t ubase = (size_t)u * I * HID;

    // ---------- phase 1 ----------
    for (int ic = 0; ic < I / NC; ++ic) {
        f32x4 accg[2][2] = {};
        f32x4 accu[2][2] = {};
        const u16* wgp = wgt + ubase + (size_t)(ic * NC) * HID;
        const u16* wup = wut + ubase + (size_t)(ic * NC) * HID;
        for (int h0 = 0; h0 < HID; h0 += BK) {
            __syncthreads();
            *(uint4*)((char*)xs + xdst) = *(const uint4*)(xrow_ptr + h0 + xslot * 8);
            #pragma unroll
            for (int j = 0; j < 4; ++j) {
                int q = j * 256 + tid, r = q >> 3, s = q & 7;
                int dst = ((r * BK + s * 8) * 2) ^ ((r & 7) << 4);
                *(uint4*)((char*)ws + dst) =
                    *(const uint4*)(wgp + (size_t)r * HID + h0 + s * 8);
                *(uint4*)((char*)ws + 2 * NC * BK + dst) =
                    *(const uint4*)(wup + (size_t)r * HID + h0 + s * 8);
            }
            __syncthreads();
            #pragma unroll
            for (int ks = 0; ks < 2; ++ks) {
                bf16x8 a0 = lds_frag(xs, l15,      ks * 32 + lg * 8, BK * 2);
                bf16x8 a1 = lds_frag(xs, 16 + l15, ks * 32 + lg * 8, BK * 2);
                #pragma unroll
                for (int ni = 0; ni < 2; ++ni) {
                    int nr = wid * 32 + ni * 16 + l15;
                    bf16x8 bg = lds_frag(ws,           nr, ks * 32 + lg * 8, BK * 2);
                    bf16x8 bu = lds_frag(ws + NC * BK, nr, ks * 32 + lg * 8, BK * 2);
                    accg[0][ni] = __builtin_amdgcn_mfma_f32_16x16x32_bf16(a0, bg, accg[0][ni], 0, 0, 0);
                    accg[1][ni] = __builtin_amdgcn_mfma_f32_16x16x32_bf16(a1, bg, accg[1][ni], 0, 0, 0);
                    accu[0][ni] = __builtin_amdgcn_mfma_f32_16x16x32_bf16(a0, bu, accu[0][ni], 0, 0, 0);
                    accu[1][ni] = __builtin_amdgcn_mfma_f32_16x16x32_bf16(a1, bu, accu[1][ni], 0, 0, 0);
                }
            }
        }
        // silu(g)*u -> act (bf16, swizzled).  C/D: col=lane&15, row=(lane>>4)*4+reg.
        #pragma unroll
        for (int mi = 0; mi < 2; ++mi)
        #pragma unroll
        for (int ni = 0; ni < 2; ++ni)
        #pragma unroll
        for (int r = 0; r < 4; ++r) {
            int row = mi * 16 + lg * 4 + r;
            int col = ic * NC + wid * 32 + ni * 16 + l15;
            float g = accg[mi][ni][r], uu = accu[mi][ni][r];
            float v = g / (1.f + __expf(-g)) * uu;
            int byte = ((row * I + col) * 2) ^ ((row & 7) << 4);
            *(u16*)((char*)act + byte) = f2bf(v);
        }
    }

    // ---------- phase 2 ----------
    const size_t dbase = (size_t)u * HID * I;
    for (int n0 = 0; n0 < HID; n0 += NC) {
        f32x4 acc[2][2] = {};
        const u16* wdp = wdt + dbase + (size_t)n0 * I;
        for (int k0 = 0; k0 < I; k0 += BK) {
            __syncthreads();   // also orders act writes (phase1) before act reads
            #pragma unroll
            for (int j = 0; j < 4; ++j) {
                int q = j * 256 + tid, r = q >> 3, s = q & 7;
                int dst = ((r * BK + s * 8) * 2) ^ ((r & 7) << 4);
                *(uint4*)((char*)ws + dst) =
                    *(const uint4*)(wdp + (size_t)r * I + k0 + s * 8);
            }
            __syncthreads();
            #pragma unroll
            for (int ks = 0; ks < 2; ++ks) {
                bf16x8 a0 = lds_frag(act, l15,      k0 + ks * 32 + lg * 8, I * 2);
                bf16x8 a1 = lds_frag(act, 16 + l15, k0 + ks * 32 + lg * 8, I * 2);
                #pragma unroll
                for (int ni = 0; ni < 2; ++ni) {
                    int nr = wid * 32 + ni * 16 + l15;
                    bf16x8 b = lds_frag(ws, nr, ks * 32 + lg * 8, BK * 2);
                    acc[0][ni] = __builtin_amdgcn_mfma_f32_16x16x32_bf16(a0, b, acc[0][ni], 0, 0, 0);
                    acc[1][ni] = __builtin_amdgcn_mfma_f32_16x16x32_bf16(a1, b, acc[1][ni], 0, 0, 0);
                }
            }
        }
        #pragma unroll
        for (int mi = 0; mi < 2; ++mi)
        #pragma unroll
        for (int ni = 0; ni < 2; ++ni)
        #pragma unroll
        for (int r = 0; r < 4; ++r) {
            int row = mi * 16 + lg * 4 + r;
            int trow = trow_s[row];
            if (trow >= 0) {
                int col = n0 + wid * 32 + ni * 16 + l15;
                float v = wt_s[row] * acc[mi][ni][r];
                if (STORE) out[(size_t)trow * HID + col] = v;
                else       atomAddF(out + (size_t)trow * HID + col, v);
            }
        }
    }
}

// ======================= fp32 fallback FFN (known-correct R1 path) =======================

template <int BTT>
__global__ __launch_bounds__(256) void ffn_kernel(
    const float* __restrict__ x,
    const float* __restrict__ wg_base, const float* __restrict__ wu_base,
    const float* __restrict__ wd_base, const int I,
    const int* __restrict__ counts, const int* __restrict__ lists,
    const float* __restrict__ wlists, const float wscale,
    float* __restrict__ out)
{
    constexpr int RPT   = BTT / 8;
    constexpr int ITILE = 256;
    constexpr int NSEG  = 256 / BTT;
    constexpr int FPT   = HK / NSEG;

    __shared__ float xsf[BTT * 33];
    __shared__ float actf[BTT * ITILE];
    __shared__ int   trow_s[BTT];
    __shared__ float wt_s[BTT];

    const int u = blockIdx.y;
    const int count = counts ? counts[u] : T_TOK;
    const int tj = blockIdx.x;
    if (tj * BTT >= count) return;
    const int i0 = blockIdx.z * ITILE;

    const float* wg = wg_base + (size_t)u * HID * I + i0;
    const float* wu = wu_base + (size_t)u * HID * I + i0;
    const float* wd = wd_base + (size_t)u * I * HID + (size_t)i0 * HID;
    const int*   lst = lists  ? lists  + (size_t)u * T_TOK : nullptr;
    const float* wl  = wlists ? wlists + (size_t)u * T_TOK : nullptr;

    const int tid = threadIdx.x;
    if (tid < BTT) {
        int idx = tj * BTT + tid;
        int trow = -1; float w = 0.f;
        if (idx < count) {
            trow = lst ? lst[idx] : idx;
            w = (wl ? wl[idx] : 1.f) * wscale;
        }
        trow_s[tid] = trow; wt_s[tid] = w;
    }
    __syncthreads();

    const int tr = tid >> 5, tc = tid & 31;
    const int lr = tid / NSEG;
    const int ls = (tid % NSEG) * FPT;
    const int ltrow = trow_s[lr];

    float accg[RPT][8], accu[RPT][8];
    #pragma unroll
    for (int rr = 0; rr < RPT; ++rr)
        #pragma unroll
        for (int cc = 0; cc < 8; ++cc) { accg[rr][cc] = 0.f; accu[rr][cc] = 0.f; }

    for (int h0 = 0; h0 < HID; h0 += HK) {
        __syncthreads();
        {
            float tmp[FPT];
            if (ltrow >= 0) {
                const float* xp = x + (size_t)ltrow * HID + h0 + ls;
                #pragma unroll
                for (int j = 0; j < FPT; ++j) tmp[j] = xp[j];
            } else {
                #pragma unroll
                for (int j = 0; j < FPT; ++j) tmp[j] = 0.f;
            }
            float* xd = xsf + lr * 33 + ls;
            #pragma unroll
            for (int j = 0; j < FPT; ++j) xd[j] = tmp[j];
        }
        __syncthreads();
        for (int kk = 0; kk < HK; ++kk) {
            float xv[RPT];
            #pragma unroll
            for (int rr = 0; rr < RPT; ++rr) xv[rr] = xsf[(tr * RPT + rr) * 33 + kk];
            const float* wgp = wg + (size_t)(h0 + kk) * I + tc * 8;
            const float* wup = wu + (size_t)(h0 + kk) * I + tc * 8;
            float4 g0 = ((const float4*)wgp)[0], g1 = ((const float4*)wgp)[1];
            float4 u0 = ((const float4*)wup)[0], u1 = ((const float4*)wup)[1];
            float wgv[8] = {g0.x,g0.y,g0.z,g0.w,g1.x,g1.y,g1.z,g1.w};
            float wuv[8] = {u0.x,u0.y,u0.z,u0.w,u1.x,u1.y,u1.z,u1.w};
            #pragma unroll
            for (int cc = 0; cc < 8; ++cc)
                #pragma unroll
                for (int rr = 0; rr < RPT; ++rr) {
                    accg[rr][cc] = fmaf(xv[rr], wgv[cc], accg[rr][cc]);
                    accu[rr][cc] = fmaf(xv[rr], wuv[cc], accu[rr][cc]);
                }
        }
    }

    #pragma unroll
    for (int rr = 0; rr < RPT; ++rr)
        #pragma unroll
        for (int cc = 0; cc < 8; ++cc) {
            float g = accg[rr][cc];
            float sig = 1.f / (1.f + expf(-g));
            actf[(tr * RPT + rr) * ITILE + tc * 8 + cc] = g * sig * accu[rr][cc];
        }
    __syncthreads();

    for (int hc = 0; hc < HID; hc += 256) {
        float acc[RPT][8];
        #pragma unroll
        for (int rr = 0; rr < RPT; ++rr)
            #pragma unroll
            for (int cc = 0; cc < 8; ++cc) acc[rr][cc] = 0.f;
        for (int kk = 0; kk < ITILE; ++kk) {
            float xv[RPT];
            #pragma unroll
            for (int rr = 0; rr < RPT; ++rr) xv[rr] = actf[(tr * RPT + rr) * ITILE + kk];
            const float* wdp = wd + (size_t)kk * HID + hc + tc * 8;
            float4 w0 = ((const float4*)wdp)[0], w1 = ((const float4*)wdp)[1];
            float wv[8] = {w0.x,w0.y,w0.z,w0.w,w1.x,w1.y,w1.z,w1.w};
            #pragma unroll
            for (int cc = 0; cc < 8; ++cc)
                #pragma unroll
                for (int rr = 0; rr < RPT; ++rr)
                    acc[rr][cc] = fmaf(xv[rr], wv[cc], acc[rr][cc]);
        }
        #pragma unroll
        for (int rr = 0; rr < RPT; ++rr) {
            int trow = trow_s[tr * RPT + rr];
            if (trow >= 0) {
                float w = wt_s[tr * RPT + rr];
                float* op = out + (size_t)trow * HID + hc + tc * 8;
                #pragma unroll
                for (int cc = 0; cc < 8; ++cc) atomAddF(&op[cc], w * acc[rr][cc]);
            }
        }
    }
}

// ======================= launcher =======================

extern "C" void kernel_launch(void* const* d_in, const int* in_sizes, int n_in,
                              void* d_out, int out_size, void* d_ws, size_t ws_size,
                              hipStream_t stream) {
    const float* x   = (const float*)d_in[0];
    const float* gw  = (const float*)d_in[1];
    const float* gb  = (const float*)d_in[2];
    const float* wgt = (const float*)d_in[3];
    const float* wup = (const float*)d_in[4];
    const float* wdn = (const float*)d_in[5];
    const float* shg = (const float*)d_in[6];
    const float* shu = (const float*)d_in[7];
    const float* shd = (const float*)d_in[8];
    const float* ag  = (const float*)d_in[9];
    const float* au  = (const float*)d_in[10];
    const float* ad  = (const float*)d_in[11];
    float* out = (float*)d_out;

    char* wsb = (char*)d_ws;
    int*   ecnt  = (int*)wsb;              // [32] + acnt[16] in first 256 B
    int*   acnt  = ecnt + NE;
    int*   elist = ecnt + 64;
    float* ewt   = (float*)(elist + NE * T_TOK);
    int*   alist = (int*)(ewt + NE * T_TOK);
    size_t lists_end = 256 + (size_t)(2 * NE * T_TOK + NL * T_TOK) * 4;

    size_t o = (lists_end + 255) & ~(size_t)255;
    auto take = [&](size_t elems) { size_t r = o; o += elems * 2; o = (o + 255) & ~(size_t)255; return r; };
    size_t o_xb = take((size_t)T_TOK * HID);
    size_t o_wg = take((size_t)NE * MOEI * HID);
    size_t o_wu = take((size_t)NE * MOEI * HID);
    size_t o_wd = take((size_t)NE * HID * MOEI);
    size_t o_sg = take((size_t)SHI * HID);
    size_t o_su = take((size_t)SHI * HID);
    size_t o_sd = take((size_t)HID * SHI);
    size_t o_ag = take((size_t)NL * AI * HID);
    size_t o_au = take((size_t)NL * AI * HID);
    size_t o_ad = take((size_t)NL * HID * AI);
    const bool bf16_ok = (o <= ws_size);

    if (bf16_ok) {
        u16* xb  = (u16*)(wsb + o_xb);
        u16* gwg = (u16*)(wsb + o_wg); u16* gwu = (u16*)(wsb + o_wu); u16* gwd = (u16*)(wsb + o_wd);
        u16* sgg = (u16*)(wsb + o_sg); u16* sgu = (u16*)(wsb + o_su); u16* sgd = (u16*)(wsb + o_sd);
        u16* agg = (u16*)(wsb + o_ag); u16* agu = (u16*)(wsb + o_au); u16* agd = (u16*)(wsb + o_ad);

        zc_kernel<<<dim3(1), dim3(64), 0, stream>>>(ecnt);
        convx_kernel<<<dim3(T_TOK * HID / 4 / 256), dim3(256), 0, stream>>>(x, xb);

        TDs P; int t0 = 0;
        auto add = [&](int i, const float* in, u16* op, int R, int C, int nm) {
            P.d[i].in = in; P.d[i].out = op; P.d[i].R = R; P.d[i].C = C;
            P.d[i].nm = nm; P.d[i].tile0 = t0;
            t0 += (R / 64) * (C / 32) * nm;
        };
        add(0, wgt, gwg, HID, MOEI, NE);
        add(1, wup, gwu, HID, MOEI, NE);
        add(2, wdn, gwd, MOEI, HID, NE);
        add(3, shg, sgg, HID, SHI, 1);
        add(4, shu, sgu, HID, SHI, 1);
        add(5, shd, sgd, SHI, HID, 1);
        add(6, ag,  agg, HID, AI, NL);
        add(7, au,  agu, HID, AI, NL);
        add(8, ad,  agd, AI, HID, NL);
        tconv_kernel<<<dim3(t0), dim3(256), 0, stream>>>(P);

        router_kernel<<<dim3(T_TOK), dim3(256), 0, stream>>>(
            x, gw, gb, ecnt, acnt, elist, ewt, alist);

        // shared expert first: plain stores initialize out (no zero pass needed)
        ffn_bf16_kernel<SHI, true><<<dim3(T_TOK / 32, 1), dim3(256), 0, stream>>>(
            xb, sgg, sgu, sgd, nullptr, nullptr, nullptr, 1.f, out);
        ffn_bf16_kernel<MOEI, false><<<dim3(T_TOK / 32, NE), dim3(256), 0, stream>>>(
            xb, gwg, gwu, gwd, ecnt, elist, ewt, 1.f, out);
        ffn_bf16_kernel<AI, false><<<dim3(T_TOK / 32, NL), dim3(256), 0, stream>>>(
            xb, agg, agu, agd, acnt, alist, nullptr, AALPHA, out);
    } else {
        // fp32 fallback (R1 path)
        zero_kernel<<<dim3((T_TOK * HID + 255) / 256), dim3(256), 0, stream>>>(
            out, T_TOK * HID, ecnt, NE + NL);
        router_kernel<<<dim3(T_TOK), dim3(256), 0, stream>>>(
            x, gw, gb, ecnt, acnt, elist, ewt, alist);
        ffn_kernel<16><<<dim3(T_TOK / 16, 1, 2), dim3(256), 0, stream>>>(
            x, shg, shu, shd, SHI, nullptr, nullptr, nullptr, 1.f, out);
        ffn_kernel<32><<<dim3(T_TOK / 32, NE, 2), dim3(256), 0, stream>>>(
            x, wgt, wup, wdn, MOEI, ecnt, elist, ewt, 1.f, out);
        ffn_kernel<16><<<dim3(T_TOK / 16, NL, 1), dim3(256), 0, stream>>>(
            x, ag, au, ad, AI, acnt, alist, nullptr, AALPHA, out);
    }
}

// Round 3
// 444.153 us; speedup vs baseline: 7.8672x; 1.7411x over previous
//
#include <hip/hip_runtime.h>
#include <math.h>

// ---- static problem config (mirrors reference) ----
#define T_TOK 1024
#define HID   1024
#define NE    32
#define NGRP  4
#define NL    16
#define TOPK  6
#define MOEI  512
#define AI    256
#define SHI   512
#define RSCALE 0.2f
#define AALPHA 0.1f
#define NU    49            // 32 routed + 1 shared + 16 anchor

typedef unsigned short u16;
typedef unsigned int   u32;
typedef __attribute__((ext_vector_type(8))) short bf16x8;
typedef __attribute__((ext_vector_type(4))) float f32x4;

__device__ __forceinline__ void atomAddF(float* p, float v) {
    unsafeAtomicAdd(p, v);   // HW global_atomic_add_f32 on gfx950
}

__device__ __forceinline__ u16 f2bf(float f) {          // fp32 -> bf16 RN-even
    u32 u = __float_as_uint(f);
    u += 0x7FFFu + ((u >> 16) & 1u);
    return (u16)(u >> 16);
}

// swizzled LDS fragment read: row-major tile, byte ^= (row&7)<<4 spreads banks
__device__ __forceinline__ bf16x8 lds_frag(const u16* buf, int row, int k, int rowBytes) {
    int byte = row * rowBytes + k * 2;
    byte ^= (row & 7) << 4;
    return *(const bf16x8*)((const char*)buf + byte);
}

// ======================= zero / scan =======================

__global__ void zero_kernel(float* __restrict__ out, int n, int* __restrict__ c, int nc) {
    int i = blockIdx.x * blockDim.x + threadIdx.x;
    if (i < n) out[i] = 0.f;
    if (i < nc) c[i] = 0;
}

__global__ void zc_kernel(int* __restrict__ c) {
    if (threadIdx.x < 64) c[threadIdx.x] = 0;
}

// eoff[33] = exclusive scan of ecnt[32]; aoff[17] = scan of acnt[16]
__global__ void scan_kernel(int* __restrict__ cnts) {
    if (threadIdx.x == 0) {
        int* ecnt = cnts; int* acnt = cnts + 32;
        int* eoff = cnts + 48; int* aoff = cnts + 81;
        int s = 0;
        for (int i = 0; i < NE; ++i) { eoff[i] = s; s += ecnt[i]; }
        eoff[NE] = s;
        s = 0;
        for (int i = 0; i < NL; ++i) { aoff[i] = s; s += acnt[i]; }
        aoff[NL] = s;
    }
}

// ======================= router =======================

__global__ __launch_bounds__(256) void router_kernel(
    const float* __restrict__ x, const float* __restrict__ gw, const float* __restrict__ gb,
    int* __restrict__ ecnt, int* __restrict__ acnt,
    int* __restrict__ elist, float* __restrict__ ewt, int* __restrict__ alist)
{
    const int t = blockIdx.x;
    __shared__ float xs[HID];
    __shared__ float logits[NE];
    const int tid = threadIdx.x;
    ((float4*)xs)[tid] = ((const float4*)(x + (size_t)t * HID))[tid];
    __syncthreads();

    const int e = tid >> 3, sub = tid & 7;
    const float4* wp = (const float4*)(gw + (size_t)e * HID + sub * 128);
    const float4* xp = (const float4*)(xs + sub * 128);
    float s = 0.f;
    #pragma unroll
    for (int i = 0; i < 32; ++i) {
        float4 a = xp[i], b = wp[i];
        s = fmaf(a.x, b.x, s); s = fmaf(a.y, b.y, s);
        s = fmaf(a.z, b.z, s); s = fmaf(a.w, b.w, s);
    }
    s += __shfl_xor(s, 1); s += __shfl_xor(s, 2); s += __shfl_xor(s, 4);
    if (sub == 0) logits[e] = s;
    __syncthreads();

    if (tid == 0) {
        float raw[NE], sc[NE];
        #pragma unroll
        for (int i = 0; i < NE; ++i) {
            float sg = 1.f / (1.f + expf(-logits[i]));
            raw[i] = sg; sc[i] = sg + gb[i];
        }
        float gsc[NGRP];
        for (int g = 0; g < NGRP; ++g) {
            const float* p = sc + g * 8;
            float m1 = -1e30f; int i1 = 0;
            for (int i = 0; i < 8; ++i) if (p[i] > m1) { m1 = p[i]; i1 = i; }
            float m2 = -1e30f;
            for (int i = 0; i < 8; ++i) if (i != i1 && p[i] > m2) m2 = p[i];
            gsc[g] = m1 + m2;
        }
        int g1 = 0; float b1 = gsc[0];
        for (int g = 1; g < NGRP; ++g) if (gsc[g] > b1) { b1 = gsc[g]; g1 = g; }
        int g2 = 0; float b2 = -1e30f;
        for (int g = 0; g < NGRP; ++g) if (g != g1 && gsc[g] > b2) { b2 = gsc[g]; g2 = g; }
        int idx[TOPK]; float tw[TOPK]; float wsum = 0.f;
        unsigned used = 0u;
        for (int k = 0; k < TOPK; ++k) {
            float best = -1e30f; int bi = 0;
            for (int i = 0; i < NE; ++i) {
                int g = i >> 3;
                if ((g == g1 || g == g2) && !((used >> i) & 1u) && sc[i] > best) { best = sc[i]; bi = i; }
            }
            used |= 1u << bi;
            idx[k] = bi; tw[k] = raw[bi]; wsum += raw[bi];
        }
        float inv = RSCALE / (wsum + 1e-20f);
        for (int k = 0; k < TOPK; ++k) {
            int ee = idx[k];
            int pos = atomicAdd(&ecnt[ee], 1);
            elist[ee * T_TOK + pos] = t;
            ewt[ee * T_TOK + pos] = tw[k] * inv;
        }
        int lg = idx[0] >> 1;
        int pos = atomicAdd(&acnt[lg], 1);
        alist[lg * T_TOK + pos] = t;
    }
}

// ======================= bf16 pre-conversion =======================

__global__ void convx_kernel(const float* __restrict__ x, u16* __restrict__ xb) {
    int i = blockIdx.x * 256 + threadIdx.x;
    float4 v = ((const float4*)x)[i];
    ushort4 o;
    o.x = f2bf(v.x); o.y = f2bf(v.y); o.z = f2bf(v.z); o.w = f2bf(v.w);
    ((ushort4*)xb)[i] = o;
}

// transpose+convert: in fp32 [nm][R][C] -> out bf16 [nm][C][R].  Tile 64(R) x 32(C).
struct TD { const float* in; u16* out; int R, C, nm, tile0; };
struct TDs { TD d[9]; };

__global__ __launch_bounds__(256) void tconv_kernel(TDs P) {
    __shared__ u16 tile[32][65];
    int t = blockIdx.x;
    int di = 0;
    #pragma unroll
    for (int i = 1; i < 9; ++i) if (t >= P.d[i].tile0) di = i;
    const float* in = P.d[di].in;
    u16* outp = P.d[di].out;
    const int R = P.d[di].R, C = P.d[di].C;
    int lt = t - P.d[di].tile0;
    int tpm = (R / 64) * (C / 32);
    int m = lt / tpm, rem = lt % tpm;
    int ct = C / 32;
    int r0 = (rem / ct) * 64, c0 = (rem % ct) * 32;
    in   += (size_t)m * R * C;
    outp += (size_t)m * R * C;
    const int tid = threadIdx.x;
    {
        int cc = tid & 31, rr0 = tid >> 5;
        #pragma unroll
        for (int j = 0; j < 8; ++j) {
            int rr = rr0 + j * 8;
            tile[cc][rr] = f2bf(in[(size_t)(r0 + rr) * C + c0 + cc]);
        }
    }
    __syncthreads();
    {
        int rr = tid & 63, cc0 = tid >> 6;
        #pragma unroll
        for (int j = 0; j < 8; ++j) {
            int c2 = cc0 + j * 4;
            outp[(size_t)(c0 + c2) * R + r0 + rr] = tile[c2][rr];
        }
    }
}

// ======================= unified split-phase MoE FFN =======================

struct MoeP {
    const u16 *gwg, *gwu, *gwd;      // routed, transposed
    const u16 *sgg, *sgu, *sgd;      // shared, transposed
    const u16 *agg, *agu, *agd;      // anchor, transposed
    const u16 *xb;                   // [T][H]
    u16 *act_rt, *act_sh, *act_an;   // compacted activations
    const int *elist, *alist;
    const float *ewt;
    float *out;
    const int *cnts;                 // ecnt[32] acnt[16] eoff[33] aoff[17]
};

// P1: act[slot][I] = silu(X Wg) * (X Wu) for one (unit, token-tile, 128-I-chunk)
__global__ __launch_bounds__(256) void p1_kernel(MoeP P) {
    constexpr int BK = 64, NC = 128;
    constexpr int nwg = NU * 4 * 32;
    const int bid = blockIdx.x;
    const int w = (bid & 7) * (nwg >> 3) + (bid >> 3);   // XCD-cluster swizzle (nwg%8==0)
    const int tj = w & 31, ic = (w >> 5) & 3, u = w >> 7;

    const int* ecnt = P.cnts; const int* acnt = P.cnts + 32;
    const int* eoff = P.cnts + 48; const int* aoff = P.cnts + 81;
    int I, cnt; const u16 *wgp, *wup; const int* lst = nullptr; u16* actb;
    if (u < NE) {
        I = MOEI; cnt = ecnt[u]; lst = P.elist + u * T_TOK;
        wgp = P.gwg + (size_t)u * MOEI * HID; wup = P.gwu + (size_t)u * MOEI * HID;
        actb = P.act_rt + (size_t)eoff[u] * MOEI;
    } else if (u == NE) {
        I = SHI; cnt = T_TOK; wgp = P.sgg; wup = P.sgu; actb = P.act_sh;
    } else {
        int a = u - NE - 1; I = AI;
        if (ic * NC >= AI) return;
        cnt = acnt[a]; lst = P.alist + a * T_TOK;
        wgp = P.agg + (size_t)a * AI * HID; wup = P.agu + (size_t)a * AI * HID;
        actb = P.act_an + (size_t)aoff[a] * AI;
    }
    if (tj * 32 >= cnt) return;
    wgp += (size_t)(ic * NC) * HID; wup += (size_t)(ic * NC) * HID;

    __shared__ __align__(16) u16 xs[32 * BK];      // 4 KB
    __shared__ __align__(16) u16 ws[2 * NC * BK];  // 32 KB
    __shared__ int trow_s[32];

    const int tid = threadIdx.x;
    if (tid < 32) {
        int idx = tj * 32 + tid; int tr = -1;
        if (idx < cnt) tr = lst ? lst[idx] : idx;
        trow_s[tid] = tr;
    }
    __syncthreads();

    const int wid = tid >> 6, l = tid & 63, l15 = l & 15, lg = l >> 4;
    const int xr = tid >> 3, xslot = tid & 7;
    int srow = trow_s[xr]; if (srow < 0) srow = trow_s[0];
    const u16* xrow_ptr = P.xb + (size_t)srow * HID;
    const int xdst = ((xr * BK + xslot * 8) * 2) ^ ((xr & 7) << 4);

    f32x4 accg[2][2] = {};
    f32x4 accu[2][2] = {};
    for (int h0 = 0; h0 < HID; h0 += BK) {
        __syncthreads();
        *(uint4*)((char*)xs + xdst) = *(const uint4*)(xrow_ptr + h0 + xslot * 8);
        #pragma unroll
        for (int j = 0; j < 4; ++j) {
            int q = j * 256 + tid, r = q >> 3, s = q & 7;
            int dst = ((r * BK + s * 8) * 2) ^ ((r & 7) << 4);
            *(uint4*)((char*)ws + dst) =
                *(const uint4*)(wgp + (size_t)r * HID + h0 + s * 8);
            *(uint4*)((char*)ws + 2 * NC * BK + dst) =
                *(const uint4*)(wup + (size_t)r * HID + h0 + s * 8);
        }
        __syncthreads();
        #pragma unroll
        for (int ks = 0; ks < 2; ++ks) {
            bf16x8 a0 = lds_frag(xs, l15,      ks * 32 + lg * 8, BK * 2);
            bf16x8 a1 = lds_frag(xs, 16 + l15, ks * 32 + lg * 8, BK * 2);
            #pragma unroll
            for (int ni = 0; ni < 2; ++ni) {
                int nr = wid * 32 + ni * 16 + l15;
                bf16x8 bg = lds_frag(ws,           nr, ks * 32 + lg * 8, BK * 2);
                bf16x8 bu = lds_frag(ws + NC * BK, nr, ks * 32 + lg * 8, BK * 2);
                accg[0][ni] = __builtin_amdgcn_mfma_f32_16x16x32_bf16(a0, bg, accg[0][ni], 0, 0, 0);
                accg[1][ni] = __builtin_amdgcn_mfma_f32_16x16x32_bf16(a1, bg, accg[1][ni], 0, 0, 0);
                accu[0][ni] = __builtin_amdgcn_mfma_f32_16x16x32_bf16(a0, bu, accu[0][ni], 0, 0, 0);
                accu[1][ni] = __builtin_amdgcn_mfma_f32_16x16x32_bf16(a1, bu, accu[1][ni], 0, 0, 0);
            }
        }
    }
    // C/D: col=lane&15, row=(lane>>4)*4+reg (m89 layout, verified in R2)
    #pragma unroll
    for (int mi = 0; mi < 2; ++mi)
    #pragma unroll
    for (int ni = 0; ni < 2; ++ni)
    #pragma unroll
    for (int r = 0; r < 4; ++r) {
        int row = mi * 16 + lg * 4 + r;
        if (trow_s[row] >= 0) {
            int col = ic * NC + wid * 32 + ni * 16 + l15;
            float g = accg[mi][ni][r], uu = accu[mi][ni][r];
            float v = g / (1.f + __expf(-g)) * uu;
            actb[(size_t)(tj * 32 + row) * I + col] = f2bf(v);
        }
    }
}

// P2: out[trow] += wt * act Wd for one (unit, token-tile, 128-H-chunk)
__global__ __launch_bounds__(256) void p2_kernel(MoeP P) {
    constexpr int BK = 64, NC = 128;
    constexpr int nwg = NU * 8 * 32;
    const int bid = blockIdx.x;
    const int w = (bid & 7) * (nwg >> 3) + (bid >> 3);
    const int tj = w & 31, nc = (w >> 5) & 7, u = w >> 8;

    const int* ecnt = P.cnts; const int* acnt = P.cnts + 32;
    const int* eoff = P.cnts + 48; const int* aoff = P.cnts + 81;
    int I, cnt; const u16* wdp; const u16* actb;
    if (u < NE) {
        I = MOEI; cnt = ecnt[u];
        wdp = P.gwd + (size_t)u * HID * MOEI; actb = P.act_rt + (size_t)eoff[u] * MOEI;
    } else if (u == NE) {
        I = SHI; cnt = T_TOK; wdp = P.sgd; actb = P.act_sh;
    } else {
        int a = u - NE - 1; I = AI; cnt = acnt[a];
        wdp = P.agd + (size_t)a * HID * AI; actb = P.act_an + (size_t)aoff[a] * AI;
    }
    if (tj * 32 >= cnt) return;
    const int n0 = nc * NC;
    wdp += (size_t)n0 * I;

    __shared__ __align__(16) u16 as_[32 * BK];   // 4 KB
    __shared__ __align__(16) u16 ws[NC * BK];    // 16 KB
    __shared__ int trow_s[32];
    __shared__ float wt_s[32];

    const int tid = threadIdx.x;
    if (tid < 32) {
        int idx = tj * 32 + tid; int tr = -1; float wv = 0.f;
        if (idx < cnt) {
            if (u < NE)      { tr = P.elist[u * T_TOK + idx]; wv = P.ewt[u * T_TOK + idx]; }
            else if (u == NE){ tr = idx; wv = 1.f; }
            else             { tr = P.alist[(u - NE - 1) * T_TOK + idx]; wv = AALPHA; }
        }
        trow_s[tid] = tr; wt_s[tid] = wv;
    }
    __syncthreads();

    const int wid = tid >> 6, l = tid & 63, l15 = l & 15, lg = l >> 4;
    const int ar = tid >> 3, aslot = tid & 7;
    const int adst = ((ar * BK + aslot * 8) * 2) ^ ((ar & 7) << 4);
    const u16* arow_ptr = actb + (size_t)(tj * 32 + ar) * I;   // pad rows: in-bounds garbage, masked at store

    f32x4 acc[2][2] = {};
    for (int k0 = 0; k0 < I; k0 += BK) {
        __syncthreads();
        *(uint4*)((char*)as_ + adst) = *(const uint4*)(arow_ptr + k0 + aslot * 8);
        #pragma unroll
        for (int j = 0; j < 4; ++j) {
            int q = j * 256 + tid, r = q >> 3, s = q & 7;
            int dst = ((r * BK + s * 8) * 2) ^ ((r & 7) << 4);
            *(uint4*)((char*)ws + dst) =
                *(const uint4*)(wdp + (size_t)r * I + k0 + s * 8);
        }
        __syncthreads();
        #pragma unroll
        for (int ks = 0; ks < 2; ++ks) {
            bf16x8 a0 = lds_frag(as_, l15,      ks * 32 + lg * 8, BK * 2);
            bf16x8 a1 = lds_frag(as_, 16 + l15, ks * 32 + lg * 8, BK * 2);
            #pragma unroll
            for (int ni = 0; ni < 2; ++ni) {
                int nr = wid * 32 + ni * 16 + l15;
                bf16x8 b = lds_frag(ws, nr, ks * 32 + lg * 8, BK * 2);
                acc[0][ni] = __builtin_amdgcn_mfma_f32_16x16x32_bf16(a0, b, acc[0][ni], 0, 0, 0);
                acc[1][ni] = __builtin_amdgcn_mfma_f32_16x16x32_bf16(a1, b, acc[1][ni], 0, 0, 0);
            }
        }
    }
    #pragma unroll
    for (int mi = 0; mi < 2; ++mi)
    #pragma unroll
    for (int ni = 0; ni < 2; ++ni)
    #pragma unroll
    for (int r = 0; r < 4; ++r) {
        int row = mi * 16 + lg * 4 + r;
        int trow = trow_s[row];
        if (trow >= 0) {
            int col = n0 + wid * 32 + ni * 16 + l15;
            atomAddF(P.out + (size_t)trow * HID + col, wt_s[row] * acc[mi][ni][r]);
        }
    }
}

// ======================= tier-b fallback: R2 fused bf16 kernel =======================

template<int I, bool STORE>
__global__ __launch_bounds__(256) void ffn_bf16_kernel(
    const u16* __restrict__ xb, const u16* __restrict__ wgt,
    const u16* __restrict__ wut, const u16* __restrict__ wdt,
    const int* __restrict__ counts, const int* __restrict__ lists,
    const float* __restrict__ wlists, const float wscale,
    float* __restrict__ out)
{
    constexpr int BT = 32, NC = 128, BK = 64;
    __shared__ __align__(16) u16 xs[BT * BK];
    __shared__ __align__(16) u16 ws[2 * NC * BK];
    __shared__ __align__(16) u16 act[BT * I];
    __shared__ int   trow_s[BT];
    __shared__ float wt_s[BT];

    const int u = blockIdx.y;
    const int count = counts ? counts[u] : T_TOK;
    const int tj = blockIdx.x;
    if (tj * BT >= count) return;

    const int tid = threadIdx.x;
    if (tid < BT) {
        int idx = tj * BT + tid; int trow = -1; float w = 0.f;
        if (idx < count) {
            trow = lists ? lists[u * T_TOK + idx] : idx;
            w = (wlists ? wlists[u * T_TOK + idx] : 1.f) * wscale;
        }
        trow_s[tid] = trow; wt_s[tid] = w;
    }
    __syncthreads();

    const int wid = tid >> 6, l = tid & 63, l15 = l & 15, lg = l >> 4;
    const int xr = tid >> 3, xslot = tid & 7;
    int srow = trow_s[xr]; if (srow < 0) srow = trow_s[0];
    const u16* xrow_ptr = xb + (size_t)srow * HID;
    const int xdst = ((xr * BK + xslot * 8) * 2) ^ ((xr & 7) << 4);
    const size_t ubase = (size_t)u * I * HID;

    for (int ic = 0; ic < I / NC; ++ic) {
        f32x4 accg[2][2] = {};
        f32x4 accu[2][2] = {};
        const u16* wgp = wgt + ubase + (size_t)(ic * NC) * HID;
        const u16* wup = wut + ubase + (size_t)(ic * NC) * HID;
        for (int h0 = 0; h0 < HID; h0 += BK) {
            __syncthreads();
            *(uint4*)((char*)xs + xdst) = *(const uint4*)(xrow_ptr + h0 + xslot * 8);
            #pragma unroll
            for (int j = 0; j < 4; ++j) {
                int q = j * 256 + tid, r = q >> 3, s = q & 7;
                int dst = ((r * BK + s * 8) * 2) ^ ((r & 7) << 4);
                *(uint4*)((char*)ws + dst) =
                    *(const uint4*)(wgp + (size_t)r * HID + h0 + s * 8);
                *(uint4*)((char*)ws + 2 * NC * BK + dst) =
                    *(const uint4*)(wup + (size_t)r * HID + h0 + s * 8);
            }
            __syncthreads();
            #pragma unroll
            for (int ks = 0; ks < 2; ++ks) {
                bf16x8 a0 = lds_frag(xs, l15,      ks * 32 + lg * 8, BK * 2);
                bf16x8 a1 = lds_frag(xs, 16 + l15, ks * 32 + lg * 8, BK * 2);
                #pragma unroll
                for (int ni = 0; ni < 2; ++ni) {
                    int nr = wid * 32 + ni * 16 + l15;
                    bf16x8 bg = lds_frag(ws,           nr, ks * 32 + lg * 8, BK * 2);
                    bf16x8 bu = lds_frag(ws + NC * BK, nr, ks * 32 + lg * 8, BK * 2);
                    accg[0][ni] = __builtin_amdgcn_mfma_f32_16x16x32_bf16(a0, bg, accg[0][ni], 0, 0, 0);
                    accg[1][ni] = __builtin_amdgcn_mfma_f32_16x16x32_bf16(a1, bg, accg[1][ni], 0, 0, 0);
                    accu[0][ni] = __builtin_amdgcn_mfma_f32_16x16x32_bf16(a0, bu, accu[0][ni], 0, 0, 0);
                    accu[1][ni] = __builtin_amdgcn_mfma_f32_16x16x32_bf16(a1, bu, accu[1][ni], 0, 0, 0);
                }
            }
        }
        #pragma unroll
        for (int mi = 0; mi < 2; ++mi)
        #pragma unroll
        for (int ni = 0; ni < 2; ++ni)
        #pragma unroll
        for (int r = 0; r < 4; ++r) {
            int row = mi * 16 + lg * 4 + r;
            int col = ic * NC + wid * 32 + ni * 16 + l15;
            float g = accg[mi][ni][r], uu = accu[mi][ni][r];
            float v = g / (1.f + __expf(-g)) * uu;
            int byte = ((row * I + col) * 2) ^ ((row & 7) << 4);
            *(u16*)((char*)act + byte) = f2bf(v);
        }
    }

    const size_t dbase = (size_t)u * HID * I;
    for (int n0 = 0; n0 < HID; n0 += NC) {
        f32x4 acc[2][2] = {};
        const u16* wdp = wdt + dbase + (size_t)n0 * I;
        for (int k0 = 0; k0 < I; k0 += BK) {
            __syncthreads();
            #pragma unroll
            for (int j = 0; j < 4; ++j) {
                int q = j * 256 + tid, r = q >> 3, s = q & 7;
                int dst = ((r * BK + s * 8) * 2) ^ ((r & 7) << 4);
                *(uint4*)((char*)ws + dst) =
                    *(const uint4*)(wdp + (size_t)r * I + k0 + s * 8);
            }
            __syncthreads();
            #pragma unroll
            for (int ks = 0; ks < 2; ++ks) {
                bf16x8 a0 = lds_frag(act, l15,      k0 + ks * 32 + lg * 8, I * 2);
                bf16x8 a1 = lds_frag(act, 16 + l15, k0 + ks * 32 + lg * 8, I * 2);
                #pragma unroll
                for (int ni = 0; ni < 2; ++ni) {
                    int nr = wid * 32 + ni * 16 + l15;
                    bf16x8 b = lds_frag(ws, nr, ks * 32 + lg * 8, BK * 2);
                    acc[0][ni] = __builtin_amdgcn_mfma_f32_16x16x32_bf16(a0, b, acc[0][ni], 0, 0, 0);
                    acc[1][ni] = __builtin_amdgcn_mfma_f32_16x16x32_bf16(a1, b, acc[1][ni], 0, 0, 0);
                }
            }
        }
        #pragma unroll
        for (int mi = 0; mi < 2; ++mi)
        #pragma unroll
        for (int ni = 0; ni < 2; ++ni)
        #pragma unroll
        for (int r = 0; r < 4; ++r) {
            int row = mi * 16 + lg * 4 + r;
            int trow = trow_s[row];
            if (trow >= 0) {
                int col = n0 + wid * 32 + ni * 16 + l15;
                float v = wt_s[row] * acc[mi][ni][r];
                if (STORE) out[(size_t)trow * HID + col] = v;
                else       atomAddF(out + (size_t)trow * HID + col, v);
            }
        }
    }
}

// ======================= launcher =======================

extern "C" void kernel_launch(void* const* d_in, const int* in_sizes, int n_in,
                              void* d_out, int out_size, void* d_ws, size_t ws_size,
                              hipStream_t stream) {
    const float* x   = (const float*)d_in[0];
    const float* gw  = (const float*)d_in[1];
    const float* gb  = (const float*)d_in[2];
    const float* wgt = (const float*)d_in[3];
    const float* wup = (const float*)d_in[4];
    const float* wdn = (const float*)d_in[5];
    const float* shg = (const float*)d_in[6];
    const float* shu = (const float*)d_in[7];
    const float* shd = (const float*)d_in[8];
    const float* ag  = (const float*)d_in[9];
    const float* au  = (const float*)d_in[10];
    const float* ad  = (const float*)d_in[11];
    float* out = (float*)d_out;

    char* wsb = (char*)d_ws;
    // header ints: ecnt[32] acnt[16] eoff[33] aoff[17] -> 98 ints, header 512 B
    int*   cnts  = (int*)wsb;
    int*   ecnt  = cnts;
    int*   acnt  = cnts + 32;
    int*   elist = (int*)(wsb + 512);
    float* ewt   = (float*)(elist + NE * T_TOK);
    int*   alist = (int*)(ewt + NE * T_TOK);
    size_t lists_end = 512 + (size_t)(2 * NE * T_TOK + NL * T_TOK) * 4;

    size_t o = (lists_end + 255) & ~(size_t)255;
    auto take = [&](size_t elems) { size_t r = o; o += elems * 2; o = (o + 255) & ~(size_t)255; return r; };
    size_t o_xb = take((size_t)T_TOK * HID);
    size_t o_wg = take((size_t)NE * MOEI * HID);
    size_t o_wu = take((size_t)NE * MOEI * HID);
    size_t o_wd = take((size_t)NE * HID * MOEI);
    size_t o_sg = take((size_t)SHI * HID);
    size_t o_su = take((size_t)SHI * HID);
    size_t o_sd = take((size_t)HID * SHI);
    size_t o_ag = take((size_t)NL * AI * HID);
    size_t o_au = take((size_t)NL * AI * HID);
    size_t o_ad = take((size_t)NL * HID * AI);
    const size_t o_weights_end = o;
    size_t o_art = take((size_t)(TOPK * T_TOK + 32) * MOEI);   // 6176 rows
    size_t o_ash = take((size_t)T_TOK * SHI);
    size_t o_aan = take((size_t)(T_TOK + 32) * AI);

    const bool tier_a = (o <= ws_size);
    const bool tier_b = (o_weights_end <= ws_size);
    if (!tier_b) return;   // proven false on this harness (R2 ran the bf16 path)

    u16* xb  = (u16*)(wsb + o_xb);
    u16* gwg = (u16*)(wsb + o_wg); u16* gwu = (u16*)(wsb + o_wu); u16* gwd = (u16*)(wsb + o_wd);
    u16* sgg = (u16*)(wsb + o_sg); u16* sgu = (u16*)(wsb + o_su); u16* sgd = (u16*)(wsb + o_sd);
    u16* agg = (u16*)(wsb + o_ag); u16* agu = (u16*)(wsb + o_au); u16* agd = (u16*)(wsb + o_ad);

    convx_kernel<<<dim3(T_TOK * HID / 4 / 256), dim3(256), 0, stream>>>(x, xb);
    TDs P; int t0 = 0;
    auto add = [&](int i, const float* in, u16* op, int R, int C, int nm) {
        P.d[i].in = in; P.d[i].out = op; P.d[i].R = R; P.d[i].C = C;
        P.d[i].nm = nm; P.d[i].tile0 = t0;
        t0 += (R / 64) * (C / 32) * nm;
    };
    add(0, wgt, gwg, HID, MOEI, NE);
    add(1, wup, gwu, HID, MOEI, NE);
    add(2, wdn, gwd, MOEI, HID, NE);
    add(3, shg, sgg, HID, SHI, 1);
    add(4, shu, sgu, HID, SHI, 1);
    add(5, shd, sgd, SHI, HID, 1);
    add(6, ag,  agg, HID, AI, NL);
    add(7, au,  agu, HID, AI, NL);
    add(8, ad,  agd, AI, HID, NL);
    tconv_kernel<<<dim3(t0), dim3(256), 0, stream>>>(P);

    if (tier_a) {
        zero_kernel<<<dim3((T_TOK * HID + 255) / 256), dim3(256), 0, stream>>>(
            out, T_TOK * HID, ecnt, 48);
        router_kernel<<<dim3(T_TOK), dim3(256), 0, stream>>>(
            x, gw, gb, ecnt, acnt, elist, ewt, alist);
        scan_kernel<<<dim3(1), dim3(64), 0, stream>>>(cnts);

        MoeP MP;
        MP.gwg = gwg; MP.gwu = gwu; MP.gwd = gwd;
        MP.sgg = sgg; MP.sgu = sgu; MP.sgd = sgd;
        MP.agg = agg; MP.agu = agu; MP.agd = agd;
        MP.xb = xb;
        MP.act_rt = (u16*)(wsb + o_art);
        MP.act_sh = (u16*)(wsb + o_ash);
        MP.act_an = (u16*)(wsb + o_aan);
        MP.elist = elist; MP.alist = alist; MP.ewt = ewt;
        MP.out = out; MP.cnts = cnts;

        p1_kernel<<<dim3(NU * 4 * 32), dim3(256), 0, stream>>>(MP);
        p2_kernel<<<dim3(NU * 8 * 32), dim3(256), 0, stream>>>(MP);
    } else {
        // tier-b: R2 fused path
        zc_kernel<<<dim3(1), dim3(64), 0, stream>>>(ecnt);
        router_kernel<<<dim3(T_TOK), dim3(256), 0, stream>>>(
            x, gw, gb, ecnt, acnt, elist, ewt, alist);
        ffn_bf16_kernel<SHI, true><<<dim3(T_TOK / 32, 1), dim3(256), 0, stream>>>(
            xb, sgg, sgu, sgd, nullptr, nullptr, nullptr, 1.f, out);
        ffn_bf16_kernel<MOEI, false><<<dim3(T_TOK / 32, NE), dim3(256), 0, stream>>>(
            xb, gwg, gwu, gwd, ecnt, elist, ewt, 1.f, out);
        ffn_bf16_kernel<AI, false><<<dim3(T_TOK / 32, NL), dim3(256), 0, stream>>>(
            xb, agg, agu, agd, acnt, alist, nullptr, AALPHA, out);
    }
}